// Round 10
// baseline (1558.349 us; speedup 1.0000x reference)
//
#include <hip/hip_runtime.h>

#define NB    32
#define SEQ   128
#define WCH   20
#define CED   50
#define NFLT  64
#define WDIM  300
#define HD    512
#define NWORD 4096
#define LPAD  11
#define NEGV  -10000.0f
#define LSTM_BLOCKS 16
#define CONV_WPB 16

typedef float f32x4 __attribute__((ext_vector_type(4)));
typedef float f32x16 __attribute__((ext_vector_type(16)));
typedef __bf16 bf16x8 __attribute__((ext_vector_type(8)));
typedef unsigned short u16x8 __attribute__((ext_vector_type(8)));
typedef unsigned short u16x4 __attribute__((ext_vector_type(4)));
typedef unsigned long long ull;

static __device__ __forceinline__ unsigned short f2bf(float f) {
  unsigned u = __builtin_bit_cast(unsigned, f);
  u += 0x7fffu + ((u >> 16) & 1u);
  return (unsigned short)(u >> 16);
}
static __device__ __forceinline__ float bf2f(unsigned short s) {
  unsigned u = ((unsigned)s) << 16;
  return __builtin_bit_cast(float, u);
}
static __device__ __forceinline__ float sigf(float x) { return 1.0f / (1.0f + expf(-x)); }

// ---------------------------------------------------------------- merged f32->bf16 converts (6 segments)
__global__ void cvt6_kernel(const float* __restrict__ s0, unsigned short* __restrict__ d0,
                            const float* __restrict__ s1, unsigned short* __restrict__ d1,
                            const float* __restrict__ s2, unsigned short* __restrict__ d2,
                            const float* __restrict__ s3, unsigned short* __restrict__ d3,
                            const float* __restrict__ s4, unsigned short* __restrict__ d4,
                            const float* __restrict__ s5, unsigned short* __restrict__ d5)
{
  // quad counts: 19200 | 22500 | 22500 | 22500 | 153600 | 153600  (cum 393900)
  int i = blockIdx.x * 256 + threadIdx.x;
  const float* src; unsigned short* dst; int k;
  if      (i < 19200)  { src = s0; dst = d0; k = i; }
  else if (i < 41700)  { src = s1; dst = d1; k = i - 19200; }
  else if (i < 64200)  { src = s2; dst = d2; k = i - 41700; }
  else if (i < 86700)  { src = s3; dst = d3; k = i - 64200; }
  else if (i < 240300) { src = s4; dst = d4; k = i - 86700; }
  else if (i < 393900) { src = s5; dst = d5; k = i - 240300; }
  else return;
  f32x4 v = *(const f32x4*)&src[k * 4];
  u16x4 o;
  #pragma unroll
  for (int j = 0; j < 4; j++) o[j] = f2bf(v[j]);
  *(u16x4*)&dst[k * 4] = o;
}

// ---------------------------------------------------------------- char CNN v2: 16 words/block, LDS bf16 weights
__global__ __launch_bounds__(256) void conv_kernel(
    const int* __restrict__ char_ids, const float* __restrict__ char_embed,
    const float* __restrict__ w2, const float* __restrict__ b2,
    const float* __restrict__ w3, const float* __restrict__ b3,
    const float* __restrict__ w4, const float* __restrict__ b4,
    const float* __restrict__ w5, const float* __restrict__ b5,
    unsigned short* __restrict__ ch)
{
  __shared__ __align__(16) unsigned short wS[44800];   // [k-seg][dw][c][f] bf16, 89.6KB
  __shared__ __align__(16) float xT[CED][WCH];
  __shared__ int idsS[WCH];
  int tid = threadIdx.x;
  int w = tid >> 6, f = tid & 63;
  int k = w + 2;
  int P = WCH - k + 1;

  // stage all conv weights once (f32 -> bf16)
  for (int e = tid; e < 44800; e += 256) {
    float v;
    if      (e < 6400)  v = w2[e];
    else if (e < 16000) v = w3[e - 6400];
    else if (e < 28800) v = w4[e - 16000];
    else                v = w5[e - 28800];
    wS[e] = f2bf(v);
  }
  const int offs = (w == 0) ? 0 : (w == 1) ? 6400 : (w == 2) ? 16000 : 28800;
  const float* cb = (w == 0) ? b2 : (w == 1) ? b3 : (w == 2) ? b4 : b5;
  float cbv = cb[f];

  for (int i = 0; i < CONV_WPB; i++) {
    int wi = blockIdx.x * CONV_WPB + i;
    __syncthreads();                       // xT/ids safe to overwrite
    if (tid < WCH) idsS[tid] = char_ids[wi * WCH + tid];
    __syncthreads();
    for (int e = tid; e < WCH * CED; e += 256) {
      int p = e / CED, c = e - p * CED;
      xT[c][p] = char_embed[idsS[p] * CED + c];
    }
    __syncthreads();

    float acc[19];
    #pragma unroll
    for (int p = 0; p < 19; p++) acc[p] = 0.f;
    for (int c = 0; c < CED; c++) {
      float xr[20];
      const float4* rowp = (const float4*)&xT[c][0];
      #pragma unroll
      for (int q = 0; q < 5; q++) {
        float4 v = rowp[q];
        xr[4*q+0] = v.x; xr[4*q+1] = v.y; xr[4*q+2] = v.z; xr[4*q+3] = v.w;
      }
      #pragma unroll
      for (int dw = 0; dw < 5; dw++) {
        if (dw < k) {
          float wv = bf2f(wS[offs + (dw * CED + c) * NFLT + f]);
          #pragma unroll
          for (int p = 0; p < 19; p++) {
            if (p < P) acc[p] += xr[p + dw] * wv;
          }
        }
      }
    }
    float m = acc[0];
    #pragma unroll
    for (int p = 1; p < 19; p++) if (p < P) m = fmaxf(m, acc[p]);
    ch[wi * 256 + w * 64 + f] = f2bf(fmaxf(0.f, m + cbv));
  }
}

// ---------------------------------------------------------------- word gather (bf16 out)
__global__ void gather_word_kernel(const int* __restrict__ token_ids,
                                   const float* __restrict__ word_embed,
                                   unsigned short* __restrict__ word_in)
{
  int idx = blockIdx.x * 256 + threadIdx.x;
  if (idx < NWORD * WDIM) {
    int i = idx / WDIM, c = idx - i * WDIM;
    word_in[idx] = f2bf(word_embed[token_ids[i] * WDIM + c]);
  }
}

// ---------------------------------------------------------------- bf16 GEMM, 256x128 tile, dual-A/B concat-K
__global__ __launch_bounds__(512) void gemm2_kernel(
    const unsigned short* __restrict__ A1, const unsigned short* __restrict__ A2,
    const unsigned short* __restrict__ B1, const unsigned short* __restrict__ B2,
    const float* __restrict__ bias, unsigned short* __restrict__ Cbf,
    int M, int N, int K1, int K2, int act, int gridN)
{
  const int Kt = K1 + K2;
  __shared__ __align__(16) unsigned short As[256 * 40];
  __shared__ __align__(16) unsigned short Bs[128 * 40];
  int bid = blockIdx.x;
  int tm = bid / gridN, tn = bid - tm * gridN;
  int m0 = tm * 256, n0 = tn * 128;
  int tid = threadIdx.x;
  int lane = tid & 63, w = tid >> 6;
  int wr = (w >> 1) * 64, wc = (w & 1) * 64;
  f32x4 acc[4][4] = {};
  int fr = lane & 15, fk = (lane >> 4) * 8;

  for (int k0 = 0; k0 < Kt; k0 += 32) {
    __syncthreads();
    #pragma unroll
    for (int i = 0; i < 4; i++) {
      int q = tid + i * 512;
      int r = q >> 3, c4 = q & 7;
      int kx = k0 + c4 * 4;
      int ra = m0 + r;
      u16x4 v = {0, 0, 0, 0};
      if (kx < Kt && ra < M) {
        v = (kx < K1) ? *(const u16x4*)&A1[(size_t)ra * K1 + kx]
                      : *(const u16x4*)&A2[(size_t)ra * K2 + (kx - K1)];
      }
      *(u16x4*)&As[r * 40 + c4 * 4] = v;
    }
    #pragma unroll
    for (int i = 0; i < 2; i++) {
      int q = tid + i * 512;
      int r = q >> 3, c4 = q & 7;
      int kx = k0 + c4 * 4;
      int rb = n0 + r;
      u16x4 v = {0, 0, 0, 0};
      if (kx < Kt && rb < N) {
        v = (kx < K1) ? *(const u16x4*)&B1[(size_t)rb * K1 + kx]
                      : *(const u16x4*)&B2[(size_t)rb * K2 + (kx - K1)];
      }
      *(u16x4*)&Bs[r * 40 + c4 * 4] = v;
    }
    __syncthreads();
    bf16x8 a[4], b[4];
    #pragma unroll
    for (int mt = 0; mt < 4; mt++)
      a[mt] = *(const bf16x8*)&As[(wr + mt * 16 + fr) * 40 + fk];
    #pragma unroll
    for (int nt = 0; nt < 4; nt++)
      b[nt] = *(const bf16x8*)&Bs[(wc + nt * 16 + fr) * 40 + fk];
    #pragma unroll
    for (int mt = 0; mt < 4; mt++)
      #pragma unroll
      for (int nt = 0; nt < 4; nt++)
        acc[mt][nt] = __builtin_amdgcn_mfma_f32_16x16x32_bf16(a[mt], b[nt], acc[mt][nt], 0, 0, 0);
  }

  #pragma unroll
  for (int mt = 0; mt < 4; mt++) {
    #pragma unroll
    for (int nt = 0; nt < 4; nt++) {
      #pragma unroll
      for (int j = 0; j < 4; j++) {
        int row = m0 + wr + mt * 16 + (lane >> 4) * 4 + j;
        int col = n0 + wc + nt * 16 + (lane & 15);
        if (row < M && col < N) {
          float v = acc[mt][nt][j];
          if (bias) v += bias[col];
          if (act == 1)      v = tanhf(v);
          else if (act == 2) v = sigf(v);
          Cbf[(size_t)row * N + col] = f2bf(v);
        }
      }
    }
  }
}

// ---------------------------------------------------------------- gate combine (bf16) + flag reset
__global__ void feats_kernel(const unsigned short* __restrict__ g,
                             const unsigned short* __restrict__ word_in,
                             const unsigned short* __restrict__ char_in,
                             unsigned short* __restrict__ feats,
                             unsigned* __restrict__ flags)
{
  if (blockIdx.x == 0 && threadIdx.x < 32)
    __hip_atomic_store(&flags[threadIdx.x], 0u, __ATOMIC_RELAXED, __HIP_MEMORY_SCOPE_AGENT);
  int idx = blockIdx.x * 256 + threadIdx.x;
  if (idx < NWORD * WDIM) {
    float gg = bf2f(g[idx]);
    feats[idx] = f2bf(gg * bf2f(word_in[idx]) + (1.f - gg) * bf2f(char_in[idx]));
  }
}

// ---------------------------------------------------------------- bidirectional LSTM (r8, unchanged)
__global__ __launch_bounds__(512, 2) void lstm_kernel(
    const unsigned short* __restrict__ xg_f, const unsigned short* __restrict__ xg_b,
    const float* __restrict__ whh_f, const float* __restrict__ whh_b,
    const int* __restrict__ lens,
    float* __restrict__ lstm_out, unsigned short* __restrict__ h_glob,
    unsigned* __restrict__ flags)
{
  int bid = blockIdx.x;
  int dir = bid >> 3, sl = bid & 7;
  int hs0 = sl << 6;
  int tid = threadIdx.x, lane = tid & 63, w = tid >> 6;
  int g = w & 3, hc = w >> 2;
  int l31 = lane & 31, le = lane >> 5;
  const unsigned short* xg = dir ? xg_b : xg_f;
  const float* whh = dir ? whh_b : whh_f;
  unsigned short* hg = h_glob + dir * (2 * NB * HD);
  unsigned* myflags = flags + dir * 16;

  bf16x8 wf[32];
  {
    const float* src = whh + (size_t)(g * HD + hs0 + hc * 32 + l31) * HD + le * 8;
    #pragma unroll
    for (int kk = 0; kk < 32; kk++) {
      u16x8 tv;
      #pragma unroll
      for (int j = 0; j < 8; j++) tv[j] = f2bf(src[kk * 16 + j]);
      wf[kk] = __builtin_bit_cast(bf16x8, tv);
    }
  }

  __shared__ __align__(16) unsigned short hS[16384];
  __shared__ float Gs[NB][260];

  int b = tid >> 4;
  int u = (tid & 15) << 2;
  int srow = tid >> 4, sq = tid & 15;
  int mylen = lens[b];
  float c4[4] = {0.f,0.f,0.f,0.f}, hp4[4] = {0.f,0.f,0.f,0.f};

  ull xq0, xq1, xq2, xq3;
  {
    int t0 = dir ? (SEQ - 1) : 0;
    const ull* xp = (const ull*)&xg[((size_t)(b * SEQ + t0)) * 2048 + hs0 + u];
    xq0 = xp[0]; xq1 = xp[128]; xq2 = xp[256]; xq3 = xp[384];
  }

  for (int s = 0; s < SEQ; s++) {
    int t = dir ? (SEQ - 1 - s) : s;
    f32x16 acc0 = {}, acc1 = {};

    if (s > 0) {
      if (w == 0) {
        unsigned tgt = (unsigned)s;
        for (;;) {
          unsigned v = (lane < 8)
            ? __hip_atomic_load(&myflags[lane], __ATOMIC_RELAXED, __HIP_MEMORY_SCOPE_AGENT)
            : tgt;
          if (__all(v >= tgt)) break;
          __builtin_amdgcn_s_sleep(1);
        }
      }
      __syncthreads();                       // B1
      {
        const ull* hq = (const ull*)(hg + (s & 1) * (NB * HD));
        ull v[8];
        #pragma unroll
        for (int i = 0; i < 8; i++)
          v[i] = __hip_atomic_load(hq + srow * 128 + sq * 8 + i, __ATOMIC_RELAXED, __HIP_MEMORY_SCOPE_AGENT);
        int rs = ((srow ^ (sq & 7)) & 31) << 4;
        #pragma unroll
        for (int e2 = 0; e2 < 4; e2++) {
          int kk = 2 * sq + (e2 >> 1), e = e2 & 1;
          uint4 qv;
          qv.x = (unsigned)v[2*e2];     qv.y = (unsigned)(v[2*e2] >> 32);
          qv.z = (unsigned)v[2*e2+1];   qv.w = (unsigned)(v[2*e2+1] >> 32);
          *(uint4*)((char*)hS + (((kk * 2 + e) << 9) + rs)) = qv;
        }
      }
      __syncthreads();                       // B2
      #pragma unroll
      for (int kk = 0; kk < 32; kk += 2) {
        int rs = ((l31 ^ ((kk >> 1) & 7)) & 31) << 4;
        int a0off = ((kk * 2 + le) << 9) + rs;
        int a1off = ((kk * 2 + 2 + le) << 9) + rs;
        bf16x8 a0 = *(const bf16x8*)((const char*)hS + a0off);
        bf16x8 a1 = *(const bf16x8*)((const char*)hS + a1off);
        acc0 = __builtin_amdgcn_mfma_f32_32x32x16_bf16(a0, wf[kk], acc0, 0, 0, 0);
        acc1 = __builtin_amdgcn_mfma_f32_32x32x16_bf16(a1, wf[kk+1], acc1, 0, 0, 0);
      }
    }

    #pragma unroll
    for (int r = 0; r < 16; r++) {
      int bb = (r & 3) + 8 * (r >> 2) + 4 * le;
      Gs[bb][g * 64 + hc * 32 + l31] = acc0[r] + acc1[r];
    }
    __syncthreads();                         // B3

    f32x4 gi  = *(const f32x4*)&Gs[b][u];
    f32x4 gfv = *(const f32x4*)&Gs[b][64 + u];
    f32x4 ggv = *(const f32x4*)&Gs[b][128 + u];
    f32x4 gov = *(const f32x4*)&Gs[b][192 + u];
    bool mk = (t < mylen);
    f32x4 outv;
    ull hpk = 0;
    #pragma unroll
    for (int j = 0; j < 4; j++) {
      float xi = bf2f((unsigned short)(xq0 >> (16*j)));
      float xf = bf2f((unsigned short)(xq1 >> (16*j)));
      float xG = bf2f((unsigned short)(xq2 >> (16*j)));
      float xo = bf2f((unsigned short)(xq3 >> (16*j)));
      float iv = sigf(xi + gi[j]);
      float fv = sigf(xf + gfv[j]);
      float Gv = tanhf(xG + ggv[j]);
      float ov = sigf(xo + gov[j]);
      float cn = fv * c4[j] + iv * Gv;
      float hn = ov * tanhf(cn);
      if (mk) c4[j] = cn;
      float hk = mk ? hn : hp4[j];
      hp4[j] = hk;
      outv[j] = mk ? hn : 0.f;
      hpk |= ((ull)f2bf(hk)) << (16*j);
    }
    {
      ull* hd = (ull*)(hg + ((s & 1) ^ 1) * (NB * HD));
      __hip_atomic_store(&hd[(b * HD + hs0 + u) >> 2], hpk, __ATOMIC_RELAXED, __HIP_MEMORY_SCOPE_AGENT);
    }

    __syncthreads();                         // B4
    if (tid == 0)
      __hip_atomic_store(&myflags[sl], (unsigned)(s + 1), __ATOMIC_RELAXED, __HIP_MEMORY_SCOPE_AGENT);

    size_t obase = ((size_t)(b * SEQ + t)) * 1024 + dir * HD + hs0 + u;
    *(f32x4*)&lstm_out[obase] = outv;
    if (s + 1 < SEQ) {
      int tn = dir ? (SEQ - 2 - s) : (s + 1);
      const ull* xp = (const ull*)&xg[((size_t)(b * SEQ + tn)) * 2048 + hs0 + u];
      xq0 = xp[0]; xq1 = xp[128]; xq2 = xp[256]; xq3 = xp[384];
    }
  }
}

// ---------------------------------------------------------------- output projection + NEG pads
__global__ __launch_bounds__(64) void logits_kernel(
    const float* __restrict__ lstm_out, const float* __restrict__ out_w,
    const float* __restrict__ out_b, float* __restrict__ lg)
{
  int rw = blockIdx.x, j = threadIdx.x;
  const float* row = lstm_out + (size_t)rw * 1024;
  float s[9];
  #pragma unroll
  for (int l = 0; l < 9; l++) s[l] = 0.f;
  for (int e = j; e < 1024; e += 64) {
    float x = row[e];
    #pragma unroll
    for (int l = 0; l < 9; l++) s[l] += x * out_w[l * 1024 + e];
  }
  #pragma unroll
  for (int l = 0; l < 9; l++) {
    #pragma unroll
    for (int off = 32; off > 0; off >>= 1) s[l] += __shfl_xor(s[l], off);
  }
  float v = NEGV;
  if (j < 9) {
    float r = (j==0)?s[0]:(j==1)?s[1]:(j==2)?s[2]:(j==3)?s[3]:(j==4)?s[4]:
              (j==5)?s[5]:(j==6)?s[6]:(j==7)?s[7]:s[8];
    v = r + out_b[j];
  }
  if (j < LPAD) lg[(size_t)rw * LPAD + j] = v;
}

// ---------------------------------------------------------------- CRF: gold + norm + loglik (merged)
__global__ __launch_bounds__(64) void crf_kernel(
    const float* __restrict__ lg, const int* __restrict__ labels,
    const int* __restrict__ lens, const float* __restrict__ trn, float* __restrict__ out_ll)
{
  int b = blockIdx.x, i = threadIdx.x;
  int len = lens[b];
  const int* lab = labels + b * SEQ;
  const float* l0 = lg + (size_t)b * SEQ * LPAD;

  // ---- gold score (all lanes end up with the value via xor-butterfly)
  float gs = 0.f;
  for (int t = i; t < SEQ; t += 64) {
    if (t < len) {
      gs += l0[t * LPAD + lab[t]];
      if (t >= 1) gs += trn[lab[t] * LPAD + lab[t - 1]];
    }
  }
  #pragma unroll
  for (int off = 32; off > 0; off >>= 1) gs += __shfl_xor(gs, off);
  gs += trn[lab[0] * LPAD + 9];
  gs += trn[10 * LPAD + lab[len - 1]];

  // ---- norm (alpha recursion, lanes 0..10 active)
  bool act = (i < LPAD);
  float trow[LPAD];
  #pragma unroll
  for (int jj = 0; jj < LPAD; jj++) trow[jj] = act ? trn[i * LPAD + jj] : 0.f;
  float alpha = act ? (l0[i] + trow[9]) : -1e30f;

  for (int t = 1; t < SEQ; t++) {
    float vj[LPAD];
    #pragma unroll
    for (int jj = 0; jj < LPAD; jj++) vj[jj] = __shfl(alpha, jj) + trow[jj];
    float mx = vj[0];
    #pragma unroll
    for (int jj = 1; jj < LPAD; jj++) mx = fmaxf(mx, vj[jj]);
    float sum = 0.f;
    #pragma unroll
    for (int jj = 0; jj < LPAD; jj++) sum += expf(vj[jj] - mx);
    float lgv = act ? l0[t * LPAD + i] : 0.f;
    float nw = mx + logf(sum) + lgv;
    if (act && t < len) alpha = nw;
  }
  float vj[LPAD];
  #pragma unroll
  for (int jj = 0; jj < LPAD; jj++) vj[jj] = __shfl(alpha, jj) + trn[10 * LPAD + jj];
  float mx = vj[0];
  #pragma unroll
  for (int jj = 1; jj < LPAD; jj++) mx = fmaxf(mx, vj[jj]);
  float sum = 0.f;
  #pragma unroll
  for (int jj = 0; jj < LPAD; jj++) sum += expf(vj[jj] - mx);
  if (i == 0) out_ll[b] = gs - (mx + logf(sum));
}

// ================================================================ launch
extern "C" void kernel_launch(void* const* d_in, const int* in_sizes, int n_in,
                              void* d_out, int out_size, void* d_ws, size_t ws_size,
                              hipStream_t stream)
{
  (void)in_sizes; (void)n_in; (void)out_size; (void)ws_size;
  const int*   token_ids = (const int*)d_in[0];
  const int*   char_ids  = (const int*)d_in[1];
  const int*   lens      = (const int*)d_in[2];
  const int*   labels    = (const int*)d_in[3];
  const float* word_embed= (const float*)d_in[4];
  const float* char_embed= (const float*)d_in[5];
  const float* w2 = (const float*)d_in[6];  const float* cb2 = (const float*)d_in[7];
  const float* w3 = (const float*)d_in[8];  const float* cb3 = (const float*)d_in[9];
  const float* w4 = (const float*)d_in[10]; const float* cb4 = (const float*)d_in[11];
  const float* w5 = (const float*)d_in[12]; const float* cb5 = (const float*)d_in[13];
  const float* ff_w = (const float*)d_in[14]; const float* ff_b = (const float*)d_in[15];
  const float* wgate_w = (const float*)d_in[16];
  const float* cgate_w = (const float*)d_in[17];
  const float* gate_w  = (const float*)d_in[18];
  const float* wih_f = (const float*)d_in[19]; const float* whh_f = (const float*)d_in[20];
  const float* b_f   = (const float*)d_in[21];
  const float* wih_b = (const float*)d_in[22]; const float* whh_b = (const float*)d_in[23];
  const float* b_b   = (const float*)d_in[24];
  const float* out_w = (const float*)d_in[25]; const float* out_b = (const float*)d_in[26];
  const float* trn   = (const float*)d_in[27];

  char* ws = (char*)d_ws;
  size_t off = 0;
  auto alloc = [&](size_t bytes) { void* p = ws + off; off += (bytes + 255) & ~(size_t)255; return p; };
  unsigned short* ch_bf    = (unsigned short*)alloc((size_t)NWORD * 256 * 2);
  unsigned short* word_bf  = (unsigned short*)alloc((size_t)NWORD * WDIM * 2);
  unsigned short* char_bf  = (unsigned short*)alloc((size_t)NWORD * WDIM * 2);
  unsigned short* t1_bf    = (unsigned short*)alloc((size_t)NWORD * WDIM * 2);
  unsigned short* g_bf     = (unsigned short*)alloc((size_t)NWORD * WDIM * 2);
  unsigned short* feats_bf = (unsigned short*)alloc((size_t)NWORD * WDIM * 2);
  unsigned short* ffw_bf   = (unsigned short*)alloc((size_t)300 * 256 * 2);
  unsigned short* wgw_bf   = (unsigned short*)alloc((size_t)300 * 300 * 2);
  unsigned short* cgw_bf   = (unsigned short*)alloc((size_t)300 * 300 * 2);
  unsigned short* gw_bf    = (unsigned short*)alloc((size_t)300 * 300 * 2);
  unsigned short* wihf_bf  = (unsigned short*)alloc((size_t)2048 * 300 * 2);
  unsigned short* wihb_bf  = (unsigned short*)alloc((size_t)2048 * 300 * 2);
  unsigned short* xgf = (unsigned short*)alloc((size_t)NWORD * 2048 * 2);
  unsigned short* xgb = (unsigned short*)alloc((size_t)NWORD * 2048 * 2);
  float* lstm_o   = (float*)alloc((size_t)NWORD * 1024 * 4);
  unsigned short* hglob = (unsigned short*)alloc((size_t)2 * 2 * NB * HD * 2);
  unsigned* flags = (unsigned*)alloc(256);

  float* outp   = (float*)d_out;
  float* loglik = outp;
  float* logits = outp + NB;

  conv_kernel<<<NWORD / CONV_WPB, 256, 0, stream>>>(char_ids, char_embed, w2, cb2, w3, cb3, w4, cb4, w5, cb5, ch_bf);
  gather_word_kernel<<<(NWORD * WDIM + 255) / 256, 256, 0, stream>>>(token_ids, word_embed, word_bf);
  cvt6_kernel<<<(393900 + 255) / 256, 256, 0, stream>>>(ff_w, ffw_bf, wgate_w, wgw_bf, cgate_w, cgw_bf,
                                                        gate_w, gw_bf, wih_f, wihf_bf, wih_b, wihb_bf);
  // char_in = ch @ ff_w^T + ff_b
  gemm2_kernel<<<16 * 3, 512, 0, stream>>>(ch_bf, ch_bf, ffw_bf, ffw_bf, ff_b, char_bf,
                                           NWORD, 300, 256, 0, 0, 3);
  // t1 = tanh(word @ wgate^T + char @ cgate^T)
  gemm2_kernel<<<16 * 3, 512, 0, stream>>>(word_bf, char_bf, wgw_bf, cgw_bf, nullptr, t1_bf,
                                           NWORD, 300, 300, 300, 1, 3);
  // g = sigmoid(t1 @ gate_w^T)
  gemm2_kernel<<<16 * 3, 512, 0, stream>>>(t1_bf, t1_bf, gw_bf, gw_bf, nullptr, g_bf,
                                           NWORD, 300, 300, 0, 2, 3);
  feats_kernel<<<(NWORD * WDIM + 255) / 256, 256, 0, stream>>>(g_bf, word_bf, char_bf, feats_bf, flags);
  // xg = feats @ wih^T + b
  gemm2_kernel<<<16 * 16, 512, 0, stream>>>(feats_bf, feats_bf, wihf_bf, wihf_bf, b_f, xgf,
                                            NWORD, 2048, 300, 0, 0, 16);
  gemm2_kernel<<<16 * 16, 512, 0, stream>>>(feats_bf, feats_bf, wihb_bf, wihb_bf, b_b, xgb,
                                            NWORD, 2048, 300, 0, 0, 16);
  {
    void* args[] = { (void*)&xgf, (void*)&xgb, (void*)&whh_f, (void*)&whh_b,
                     (void*)&lens, (void*)&lstm_o, (void*)&hglob, (void*)&flags };
    hipLaunchCooperativeKernel((void*)lstm_kernel, dim3(LSTM_BLOCKS), dim3(512), args, 0, stream);
  }
  logits_kernel<<<NWORD, 64, 0, stream>>>(lstm_o, out_w, out_b, logits);
  crf_kernel<<<NB, 64, 0, stream>>>(logits, labels, lens, trn, loglik);
}

// Round 11
// 1245.386 us; speedup vs baseline: 1.2513x; 1.2513x over previous
//
#include <hip/hip_runtime.h>

#define NB    32
#define SEQ   128
#define WCH   20
#define CED   50
#define NFLT  64
#define WDIM  300
#define HD    512
#define NWORD 4096
#define LPAD  11
#define NEGV  -10000.0f
#define LSTM_BLOCKS 16

typedef float f32x4 __attribute__((ext_vector_type(4)));
typedef float f32x16 __attribute__((ext_vector_type(16)));
typedef __bf16 bf16x8 __attribute__((ext_vector_type(8)));
typedef unsigned short u16x8 __attribute__((ext_vector_type(8)));
typedef unsigned short u16x4 __attribute__((ext_vector_type(4)));
typedef unsigned long long ull;

static __device__ __forceinline__ unsigned short f2bf(float f) {
  unsigned u = __builtin_bit_cast(unsigned, f);
  u += 0x7fffu + ((u >> 16) & 1u);
  return (unsigned short)(u >> 16);
}
static __device__ __forceinline__ float bf2f(unsigned short s) {
  unsigned u = ((unsigned)s) << 16;
  return __builtin_bit_cast(float, u);
}
static __device__ __forceinline__ float sigf(float x) { return 1.0f / (1.0f + expf(-x)); }

// ---------------------------------------------------------------- merged f32->bf16 converts (6 segments)
__global__ void cvt6_kernel(const float* __restrict__ s0, unsigned short* __restrict__ d0,
                            const float* __restrict__ s1, unsigned short* __restrict__ d1,
                            const float* __restrict__ s2, unsigned short* __restrict__ d2,
                            const float* __restrict__ s3, unsigned short* __restrict__ d3,
                            const float* __restrict__ s4, unsigned short* __restrict__ d4,
                            const float* __restrict__ s5, unsigned short* __restrict__ d5)
{
  int i = blockIdx.x * 256 + threadIdx.x;
  const float* src; unsigned short* dst; int k;
  if      (i < 19200)  { src = s0; dst = d0; k = i; }
  else if (i < 41700)  { src = s1; dst = d1; k = i - 19200; }
  else if (i < 64200)  { src = s2; dst = d2; k = i - 41700; }
  else if (i < 86700)  { src = s3; dst = d3; k = i - 64200; }
  else if (i < 240300) { src = s4; dst = d4; k = i - 86700; }
  else if (i < 393900) { src = s5; dst = d5; k = i - 240300; }
  else return;
  f32x4 v = *(const f32x4*)&src[k * 4];
  u16x4 o;
  #pragma unroll
  for (int j = 0; j < 4; j++) o[j] = f2bf(v[j]);
  *(u16x4*)&dst[k * 4] = o;
}

// ---------------------------------------------------------------- char CNN (r9 per-word form, bf16 out)
__global__ __launch_bounds__(256) void conv_kernel(
    const int* __restrict__ char_ids, const float* __restrict__ char_embed,
    const float* __restrict__ w2, const float* __restrict__ b2,
    const float* __restrict__ w3, const float* __restrict__ b3,
    const float* __restrict__ w4, const float* __restrict__ b4,
    const float* __restrict__ w5, const float* __restrict__ b5,
    unsigned short* __restrict__ ch)
{
  __shared__ __align__(16) float xT[CED][WCH];
  int wi = blockIdx.x;
  int tid = threadIdx.x;
  for (int e = tid; e < WCH * CED; e += 256) {
    int p = e / CED, c = e - p * CED;
    int cid = char_ids[wi * WCH + p];
    xT[c][p] = char_embed[cid * CED + c];
  }
  __syncthreads();
  int w = tid >> 6, f = tid & 63;
  int k = w + 2;
  int P = WCH - k + 1;
  const float* cw = (w == 0) ? w2 : (w == 1) ? w3 : (w == 2) ? w4 : w5;
  const float* cb = (w == 0) ? b2 : (w == 1) ? b3 : (w == 2) ? b4 : b5;
  float acc[19];
  #pragma unroll
  for (int p = 0; p < 19; p++) acc[p] = 0.f;
  for (int c = 0; c < CED; c++) {
    float xr[20];
    const float4* rowp = (const float4*)&xT[c][0];
    #pragma unroll
    for (int q = 0; q < 5; q++) {
      float4 v = rowp[q];
      xr[4*q+0] = v.x; xr[4*q+1] = v.y; xr[4*q+2] = v.z; xr[4*q+3] = v.w;
    }
    #pragma unroll
    for (int dw = 0; dw < 5; dw++) {
      if (dw < k) {
        float wv = cw[(dw * CED + c) * NFLT + f];
        #pragma unroll
        for (int p = 0; p < 19; p++) {
          if (p < P) acc[p] += xr[p + dw] * wv;
        }
      }
    }
  }
  float m = acc[0];
  #pragma unroll
  for (int p = 1; p < 19; p++) if (p < P) m = fmaxf(m, acc[p]);
  ch[wi * 256 + w * 64 + f] = f2bf(fmaxf(0.f, m + cb[f]));
}

// ---------------------------------------------------------------- word gather (bf16 out)
__global__ void gather_word_kernel(const int* __restrict__ token_ids,
                                   const float* __restrict__ word_embed,
                                   unsigned short* __restrict__ word_in)
{
  int idx = blockIdx.x * 256 + threadIdx.x;
  if (idx < NWORD * WDIM) {
    int i = idx / WDIM, c = idx - i * WDIM;
    word_in[idx] = f2bf(word_embed[token_ids[i] * WDIM + c]);
  }
}

// ---------------------------------------------------------------- bf16 GEMM, 256x128 tile, dual-A/B concat-K
__global__ __launch_bounds__(512) void gemm2_kernel(
    const unsigned short* __restrict__ A1, const unsigned short* __restrict__ A2,
    const unsigned short* __restrict__ B1, const unsigned short* __restrict__ B2,
    const float* __restrict__ bias, unsigned short* __restrict__ Cbf,
    int M, int N, int K1, int K2, int act, int gridN)
{
  const int Kt = K1 + K2;
  __shared__ __align__(16) unsigned short As[256 * 40];
  __shared__ __align__(16) unsigned short Bs[128 * 40];
  int bid = blockIdx.x;
  int tm = bid / gridN, tn = bid - tm * gridN;
  int m0 = tm * 256, n0 = tn * 128;
  int tid = threadIdx.x;
  int lane = tid & 63, w = tid >> 6;
  int wr = (w >> 1) * 64, wc = (w & 1) * 64;
  f32x4 acc[4][4] = {};
  int fr = lane & 15, fk = (lane >> 4) * 8;

  for (int k0 = 0; k0 < Kt; k0 += 32) {
    __syncthreads();
    #pragma unroll
    for (int i = 0; i < 4; i++) {
      int q = tid + i * 512;
      int r = q >> 3, c4 = q & 7;
      int kx = k0 + c4 * 4;
      int ra = m0 + r;
      u16x4 v = {0, 0, 0, 0};
      if (kx < Kt && ra < M) {
        v = (kx < K1) ? *(const u16x4*)&A1[(size_t)ra * K1 + kx]
                      : *(const u16x4*)&A2[(size_t)ra * K2 + (kx - K1)];
      }
      *(u16x4*)&As[r * 40 + c4 * 4] = v;
    }
    #pragma unroll
    for (int i = 0; i < 2; i++) {
      int q = tid + i * 512;
      int r = q >> 3, c4 = q & 7;
      int kx = k0 + c4 * 4;
      int rb = n0 + r;
      u16x4 v = {0, 0, 0, 0};
      if (kx < Kt && rb < N) {
        v = (kx < K1) ? *(const u16x4*)&B1[(size_t)rb * K1 + kx]
                      : *(const u16x4*)&B2[(size_t)rb * K2 + (kx - K1)];
      }
      *(u16x4*)&Bs[r * 40 + c4 * 4] = v;
    }
    __syncthreads();
    bf16x8 a[4], b[4];
    #pragma unroll
    for (int mt = 0; mt < 4; mt++)
      a[mt] = *(const bf16x8*)&As[(wr + mt * 16 + fr) * 40 + fk];
    #pragma unroll
    for (int nt = 0; nt < 4; nt++)
      b[nt] = *(const bf16x8*)&Bs[(wc + nt * 16 + fr) * 40 + fk];
    #pragma unroll
    for (int mt = 0; mt < 4; mt++)
      #pragma unroll
      for (int nt = 0; nt < 4; nt++)
        acc[mt][nt] = __builtin_amdgcn_mfma_f32_16x16x32_bf16(a[mt], b[nt], acc[mt][nt], 0, 0, 0);
  }

  #pragma unroll
  for (int mt = 0; mt < 4; mt++) {
    #pragma unroll
    for (int nt = 0; nt < 4; nt++) {
      #pragma unroll
      for (int j = 0; j < 4; j++) {
        int row = m0 + wr + mt * 16 + (lane >> 4) * 4 + j;
        int col = n0 + wc + nt * 16 + (lane & 15);
        if (row < M && col < N) {
          float v = acc[mt][nt][j];
          if (bias) v += bias[col];
          if (act == 1)      v = tanhf(v);
          else if (act == 2) v = sigf(v);
          Cbf[(size_t)row * N + col] = f2bf(v);
        }
      }
    }
  }
}

// ---------------------------------------------------------------- gate combine (bf16) + flag reset
__global__ void feats_kernel(const unsigned short* __restrict__ g,
                             const unsigned short* __restrict__ word_in,
                             const unsigned short* __restrict__ char_in,
                             unsigned short* __restrict__ feats,
                             unsigned* __restrict__ flags)
{
  if (blockIdx.x == 0 && threadIdx.x < 32)
    __hip_atomic_store(&flags[threadIdx.x], 0u, __ATOMIC_RELAXED, __HIP_MEMORY_SCOPE_AGENT);
  int idx = blockIdx.x * 256 + threadIdx.x;
  if (idx < NWORD * WDIM) {
    float gg = bf2f(g[idx]);
    feats[idx] = f2bf(gg * bf2f(word_in[idx]) + (1.f - gg) * bf2f(char_in[idx]));
  }
}

// ---------------------------------------------------------------- bidirectional LSTM (r8 fabric; lstm_out now bf16)
__global__ __launch_bounds__(512, 2) void lstm_kernel(
    const unsigned short* __restrict__ xg_f, const unsigned short* __restrict__ xg_b,
    const float* __restrict__ whh_f, const float* __restrict__ whh_b,
    const int* __restrict__ lens,
    unsigned short* __restrict__ lstm_out, unsigned short* __restrict__ h_glob,
    unsigned* __restrict__ flags)
{
  int bid = blockIdx.x;
  int dir = bid >> 3, sl = bid & 7;
  int hs0 = sl << 6;
  int tid = threadIdx.x, lane = tid & 63, w = tid >> 6;
  int g = w & 3, hc = w >> 2;
  int l31 = lane & 31, le = lane >> 5;
  const unsigned short* xg = dir ? xg_b : xg_f;
  const float* whh = dir ? whh_b : whh_f;
  unsigned short* hg = h_glob + dir * (2 * NB * HD);
  unsigned* myflags = flags + dir * 16;

  bf16x8 wf[32];
  {
    const float* src = whh + (size_t)(g * HD + hs0 + hc * 32 + l31) * HD + le * 8;
    #pragma unroll
    for (int kk = 0; kk < 32; kk++) {
      u16x8 tv;
      #pragma unroll
      for (int j = 0; j < 8; j++) tv[j] = f2bf(src[kk * 16 + j]);
      wf[kk] = __builtin_bit_cast(bf16x8, tv);
    }
  }

  __shared__ __align__(16) unsigned short hS[16384];
  __shared__ float Gs[NB][260];

  int b = tid >> 4;
  int u = (tid & 15) << 2;
  int srow = tid >> 4, sq = tid & 15;
  int mylen = lens[b];
  float c4[4] = {0.f,0.f,0.f,0.f}, hp4[4] = {0.f,0.f,0.f,0.f};

  ull xq0, xq1, xq2, xq3;
  {
    int t0 = dir ? (SEQ - 1) : 0;
    const ull* xp = (const ull*)&xg[((size_t)(b * SEQ + t0)) * 2048 + hs0 + u];
    xq0 = xp[0]; xq1 = xp[128]; xq2 = xp[256]; xq3 = xp[384];
  }

  for (int s = 0; s < SEQ; s++) {
    int t = dir ? (SEQ - 1 - s) : s;
    f32x16 acc0 = {}, acc1 = {};

    if (s > 0) {
      if (w == 0) {
        unsigned tgt = (unsigned)s;
        for (;;) {
          unsigned v = (lane < 8)
            ? __hip_atomic_load(&myflags[lane], __ATOMIC_RELAXED, __HIP_MEMORY_SCOPE_AGENT)
            : tgt;
          if (__all(v >= tgt)) break;
          __builtin_amdgcn_s_sleep(1);
        }
      }
      __syncthreads();                       // B1
      {
        const ull* hq = (const ull*)(hg + (s & 1) * (NB * HD));
        ull v[8];
        #pragma unroll
        for (int i = 0; i < 8; i++)
          v[i] = __hip_atomic_load(hq + srow * 128 + sq * 8 + i, __ATOMIC_RELAXED, __HIP_MEMORY_SCOPE_AGENT);
        int rs = ((srow ^ (sq & 7)) & 31) << 4;
        #pragma unroll
        for (int e2 = 0; e2 < 4; e2++) {
          int kk = 2 * sq + (e2 >> 1), e = e2 & 1;
          uint4 qv;
          qv.x = (unsigned)v[2*e2];     qv.y = (unsigned)(v[2*e2] >> 32);
          qv.z = (unsigned)v[2*e2+1];   qv.w = (unsigned)(v[2*e2+1] >> 32);
          *(uint4*)((char*)hS + (((kk * 2 + e) << 9) + rs)) = qv;
        }
      }
      __syncthreads();                       // B2
      #pragma unroll
      for (int kk = 0; kk < 32; kk += 2) {
        int rs = ((l31 ^ ((kk >> 1) & 7)) & 31) << 4;
        int a0off = ((kk * 2 + le) << 9) + rs;
        int a1off = ((kk * 2 + 2 + le) << 9) + rs;
        bf16x8 a0 = *(const bf16x8*)((const char*)hS + a0off);
        bf16x8 a1 = *(const bf16x8*)((const char*)hS + a1off);
        acc0 = __builtin_amdgcn_mfma_f32_32x32x16_bf16(a0, wf[kk], acc0, 0, 0, 0);
        acc1 = __builtin_amdgcn_mfma_f32_32x32x16_bf16(a1, wf[kk+1], acc1, 0, 0, 0);
      }
    }

    #pragma unroll
    for (int r = 0; r < 16; r++) {
      int bb = (r & 3) + 8 * (r >> 2) + 4 * le;
      Gs[bb][g * 64 + hc * 32 + l31] = acc0[r] + acc1[r];
    }
    __syncthreads();                         // B3

    f32x4 gi  = *(const f32x4*)&Gs[b][u];
    f32x4 gfv = *(const f32x4*)&Gs[b][64 + u];
    f32x4 ggv = *(const f32x4*)&Gs[b][128 + u];
    f32x4 gov = *(const f32x4*)&Gs[b][192 + u];
    bool mk = (t < mylen);
    ull hpk = 0, opk = 0;
    #pragma unroll
    for (int j = 0; j < 4; j++) {
      float xi = bf2f((unsigned short)(xq0 >> (16*j)));
      float xf = bf2f((unsigned short)(xq1 >> (16*j)));
      float xG = bf2f((unsigned short)(xq2 >> (16*j)));
      float xo = bf2f((unsigned short)(xq3 >> (16*j)));
      float iv = sigf(xi + gi[j]);
      float fv = sigf(xf + gfv[j]);
      float Gv = tanhf(xG + ggv[j]);
      float ov = sigf(xo + gov[j]);
      float cn = fv * c4[j] + iv * Gv;
      float hn = ov * tanhf(cn);
      if (mk) c4[j] = cn;
      float hk = mk ? hn : hp4[j];
      hp4[j] = hk;
      opk |= ((ull)f2bf(mk ? hn : 0.f)) << (16*j);
      hpk |= ((ull)f2bf(hk)) << (16*j);
    }
    {
      ull* hd = (ull*)(hg + ((s & 1) ^ 1) * (NB * HD));
      __hip_atomic_store(&hd[(b * HD + hs0 + u) >> 2], hpk, __ATOMIC_RELAXED, __HIP_MEMORY_SCOPE_AGENT);
    }

    __syncthreads();                         // B4: drains all waves' h stores to L3
    if (tid == 0)
      __hip_atomic_store(&myflags[sl], (unsigned)(s + 1), __ATOMIC_RELAXED, __HIP_MEMORY_SCOPE_AGENT);

    // off-critical-path: bf16 lstm_out store + next-step xg prefetch
    size_t obase = ((size_t)(b * SEQ + t)) * 1024 + dir * HD + hs0 + u;
    *(ull*)&lstm_out[obase] = opk;
    if (s + 1 < SEQ) {
      int tn = dir ? (SEQ - 2 - s) : (s + 1);
      const ull* xp = (const ull*)&xg[((size_t)(b * SEQ + tn)) * 2048 + hs0 + u];
      xq0 = xp[0]; xq1 = xp[128]; xq2 = xp[256]; xq3 = xp[384];
    }
  }
}

// ---------------------------------------------------------------- output projection + NEG pads (bf16 in, vector loads)
__global__ __launch_bounds__(64) void logits_kernel(
    const unsigned short* __restrict__ lstm_out, const float* __restrict__ out_w,
    const float* __restrict__ out_b, float* __restrict__ lg)
{
  int rw = blockIdx.x, j = threadIdx.x;
  const unsigned short* row = lstm_out + (size_t)rw * 1024;
  u16x8 v0 = *(const u16x8*)&row[j * 16];
  u16x8 v1 = *(const u16x8*)&row[j * 16 + 8];
  float s[9];
  #pragma unroll
  for (int l = 0; l < 9; l++) s[l] = 0.f;
  #pragma unroll
  for (int k = 0; k < 8; k++) {
    float x = bf2f(v0[k]);
    int e = j * 16 + k;
    #pragma unroll
    for (int l = 0; l < 9; l++) s[l] += x * out_w[l * 1024 + e];
  }
  #pragma unroll
  for (int k = 0; k < 8; k++) {
    float x = bf2f(v1[k]);
    int e = j * 16 + 8 + k;
    #pragma unroll
    for (int l = 0; l < 9; l++) s[l] += x * out_w[l * 1024 + e];
  }
  #pragma unroll
  for (int l = 0; l < 9; l++) {
    #pragma unroll
    for (int off = 32; off > 0; off >>= 1) s[l] += __shfl_xor(s[l], off);
  }
  float v = NEGV;
  if (j < 9) {
    float r = (j==0)?s[0]:(j==1)?s[1]:(j==2)?s[2]:(j==3)?s[3]:(j==4)?s[4]:
              (j==5)?s[5]:(j==6)?s[6]:(j==7)?s[7]:s[8];
    v = r + out_b[j];
  }
  if (j < LPAD) lg[(size_t)rw * LPAD + j] = v;
}

// ---------------------------------------------------------------- CRF: gold + norm + loglik (merged)
__global__ __launch_bounds__(64) void crf_kernel(
    const float* __restrict__ lg, const int* __restrict__ labels,
    const int* __restrict__ lens, const float* __restrict__ trn, float* __restrict__ out_ll)
{
  int b = blockIdx.x, i = threadIdx.x;
  int len = lens[b];
  const int* lab = labels + b * SEQ;
  const float* l0 = lg + (size_t)b * SEQ * LPAD;

  float gs = 0.f;
  for (int t = i; t < SEQ; t += 64) {
    if (t < len) {
      gs += l0[t * LPAD + lab[t]];
      if (t >= 1) gs += trn[lab[t] * LPAD + lab[t - 1]];
    }
  }
  #pragma unroll
  for (int off = 32; off > 0; off >>= 1) gs += __shfl_xor(gs, off);
  gs += trn[lab[0] * LPAD + 9];
  gs += trn[10 * LPAD + lab[len - 1]];

  bool act = (i < LPAD);
  float trow[LPAD];
  #pragma unroll
  for (int jj = 0; jj < LPAD; jj++) trow[jj] = act ? trn[i * LPAD + jj] : 0.f;
  float alpha = act ? (l0[i] + trow[9]) : -1e30f;

  for (int t = 1; t < SEQ; t++) {
    float vj[LPAD];
    #pragma unroll
    for (int jj = 0; jj < LPAD; jj++) vj[jj] = __shfl(alpha, jj) + trow[jj];
    float mx = vj[0];
    #pragma unroll
    for (int jj = 1; jj < LPAD; jj++) mx = fmaxf(mx, vj[jj]);
    float sum = 0.f;
    #pragma unroll
    for (int jj = 0; jj < LPAD; jj++) sum += expf(vj[jj] - mx);
    float lgv = act ? l0[t * LPAD + i] : 0.f;
    float nw = mx + logf(sum) + lgv;
    if (act && t < len) alpha = nw;
  }
  float vj[LPAD];
  #pragma unroll
  for (int jj = 0; jj < LPAD; jj++) vj[jj] = __shfl(alpha, jj) + trn[10 * LPAD + jj];
  float mx = vj[0];
  #pragma unroll
  for (int jj = 1; jj < LPAD; jj++) mx = fmaxf(mx, vj[jj]);
  float sum = 0.f;
  #pragma unroll
  for (int jj = 0; jj < LPAD; jj++) sum += expf(vj[jj] - mx);
  if (i == 0) out_ll[b] = gs - (mx + logf(sum));
}

// ================================================================ launch
extern "C" void kernel_launch(void* const* d_in, const int* in_sizes, int n_in,
                              void* d_out, int out_size, void* d_ws, size_t ws_size,
                              hipStream_t stream)
{
  (void)in_sizes; (void)n_in; (void)out_size; (void)ws_size;
  const int*   token_ids = (const int*)d_in[0];
  const int*   char_ids  = (const int*)d_in[1];
  const int*   lens      = (const int*)d_in[2];
  const int*   labels    = (const int*)d_in[3];
  const float* word_embed= (const float*)d_in[4];
  const float* char_embed= (const float*)d_in[5];
  const float* w2 = (const float*)d_in[6];  const float* cb2 = (const float*)d_in[7];
  const float* w3 = (const float*)d_in[8];  const float* cb3 = (const float*)d_in[9];
  const float* w4 = (const float*)d_in[10]; const float* cb4 = (const float*)d_in[11];
  const float* w5 = (const float*)d_in[12]; const float* cb5 = (const float*)d_in[13];
  const float* ff_w = (const float*)d_in[14]; const float* ff_b = (const float*)d_in[15];
  const float* wgate_w = (const float*)d_in[16];
  const float* cgate_w = (const float*)d_in[17];
  const float* gate_w  = (const float*)d_in[18];
  const float* wih_f = (const float*)d_in[19]; const float* whh_f = (const float*)d_in[20];
  const float* b_f   = (const float*)d_in[21];
  const float* wih_b = (const float*)d_in[22]; const float* whh_b = (const float*)d_in[23];
  const float* b_b   = (const float*)d_in[24];
  const float* out_w = (const float*)d_in[25]; const float* out_b = (const float*)d_in[26];
  const float* trn   = (const float*)d_in[27];

  char* ws = (char*)d_ws;
  size_t off = 0;
  auto alloc = [&](size_t bytes) { void* p = ws + off; off += (bytes + 255) & ~(size_t)255; return p; };
  unsigned short* ch_bf    = (unsigned short*)alloc((size_t)NWORD * 256 * 2);
  unsigned short* word_bf  = (unsigned short*)alloc((size_t)NWORD * WDIM * 2);
  unsigned short* char_bf  = (unsigned short*)alloc((size_t)NWORD * WDIM * 2);
  unsigned short* t1_bf    = (unsigned short*)alloc((size_t)NWORD * WDIM * 2);
  unsigned short* g_bf     = (unsigned short*)alloc((size_t)NWORD * WDIM * 2);
  unsigned short* feats_bf = (unsigned short*)alloc((size_t)NWORD * WDIM * 2);
  unsigned short* ffw_bf   = (unsigned short*)alloc((size_t)300 * 256 * 2);
  unsigned short* wgw_bf   = (unsigned short*)alloc((size_t)300 * 300 * 2);
  unsigned short* cgw_bf   = (unsigned short*)alloc((size_t)300 * 300 * 2);
  unsigned short* gw_bf    = (unsigned short*)alloc((size_t)300 * 300 * 2);
  unsigned short* wihf_bf  = (unsigned short*)alloc((size_t)2048 * 300 * 2);
  unsigned short* wihb_bf  = (unsigned short*)alloc((size_t)2048 * 300 * 2);
  unsigned short* xgf = (unsigned short*)alloc((size_t)NWORD * 2048 * 2);
  unsigned short* xgb = (unsigned short*)alloc((size_t)NWORD * 2048 * 2);
  unsigned short* lstm_o = (unsigned short*)alloc((size_t)NWORD * 1024 * 2);
  unsigned short* hglob = (unsigned short*)alloc((size_t)2 * 2 * NB * HD * 2);
  unsigned* flags = (unsigned*)alloc(256);

  float* outp   = (float*)d_out;
  float* loglik = outp;
  float* logits = outp + NB;

  conv_kernel<<<NWORD, 256, 0, stream>>>(char_ids, char_embed, w2, cb2, w3, cb3, w4, cb4, w5, cb5, ch_bf);
  gather_word_kernel<<<(NWORD * WDIM + 255) / 256, 256, 0, stream>>>(token_ids, word_embed, word_bf);
  cvt6_kernel<<<(393900 + 255) / 256, 256, 0, stream>>>(ff_w, ffw_bf, wgate_w, wgw_bf, cgate_w, cgw_bf,
                                                        gate_w, gw_bf, wih_f, wihf_bf, wih_b, wihb_bf);
  // char_in = ch @ ff_w^T + ff_b
  gemm2_kernel<<<16 * 3, 512, 0, stream>>>(ch_bf, ch_bf, ffw_bf, ffw_bf, ff_b, char_bf,
                                           NWORD, 300, 256, 0, 0, 3);
  // t1 = tanh(word @ wgate^T + char @ cgate^T)
  gemm2_kernel<<<16 * 3, 512, 0, stream>>>(word_bf, char_bf, wgw_bf, cgw_bf, nullptr, t1_bf,
                                           NWORD, 300, 300, 300, 1, 3);
  // g = sigmoid(t1 @ gate_w^T)
  gemm2_kernel<<<16 * 3, 512, 0, stream>>>(t1_bf, t1_bf, gw_bf, gw_bf, nullptr, g_bf,
                                           NWORD, 300, 300, 0, 2, 3);
  feats_kernel<<<(NWORD * WDIM + 255) / 256, 256, 0, stream>>>(g_bf, word_bf, char_bf, feats_bf, flags);
  // xg = feats @ wih^T + b
  gemm2_kernel<<<16 * 16, 512, 0, stream>>>(feats_bf, feats_bf, wihf_bf, wihf_bf, b_f, xgf,
                                            NWORD, 2048, 300, 0, 0, 16);
  gemm2_kernel<<<16 * 16, 512, 0, stream>>>(feats_bf, feats_bf, wihb_bf, wihb_bf, b_b, xgb,
                                            NWORD, 2048, 300, 0, 0, 16);
  {
    void* args[] = { (void*)&xgf, (void*)&xgb, (void*)&whh_f, (void*)&whh_b,
                     (void*)&lens, (void*)&lstm_o, (void*)&hglob, (void*)&flags };
    hipLaunchCooperativeKernel((void*)lstm_kernel, dim3(LSTM_BLOCKS), dim3(512), args, 0, stream);
  }
  logits_kernel<<<NWORD, 64, 0, stream>>>(lstm_o, out_w, out_b, logits);
  crf_kernel<<<NB, 64, 0, stream>>>(logits, labels, lens, trn, loglik);
}

// Round 12
// 1243.045 us; speedup vs baseline: 1.2537x; 1.0019x over previous
//
#include <hip/hip_runtime.h>

#define NB    32
#define SEQ   128
#define WCH   20
#define CED   50
#define NFLT  64
#define WDIM  300
#define HD    512
#define NWORD 4096
#define LPAD  11
#define NEGV  -10000.0f
#define LSTM_BLOCKS 16

typedef float f32x4 __attribute__((ext_vector_type(4)));
typedef float f32x16 __attribute__((ext_vector_type(16)));
typedef __bf16 bf16x8 __attribute__((ext_vector_type(8)));
typedef unsigned short u16x8 __attribute__((ext_vector_type(8)));
typedef unsigned short u16x4 __attribute__((ext_vector_type(4)));
typedef unsigned long long ull;

static __device__ __forceinline__ unsigned short f2bf(float f) {
  unsigned u = __builtin_bit_cast(unsigned, f);
  u += 0x7fffu + ((u >> 16) & 1u);
  return (unsigned short)(u >> 16);
}
static __device__ __forceinline__ float bf2f(unsigned short s) {
  unsigned u = ((unsigned)s) << 16;
  return __builtin_bit_cast(float, u);
}
static __device__ __forceinline__ float sigf(float x) { return 1.0f / (1.0f + expf(-x)); }

// ---------------------------------------------------------------- merged f32->bf16 converts (6 segments)
// NOTE: wih_f (seg4) and wih_b (seg5) destinations are CONTIGUOUS in ws,
// forming one [4096][300] bf16 matrix for the merged xg GEMM.
__global__ void cvt6_kernel(const float* __restrict__ s0, unsigned short* __restrict__ d0,
                            const float* __restrict__ s1, unsigned short* __restrict__ d1,
                            const float* __restrict__ s2, unsigned short* __restrict__ d2,
                            const float* __restrict__ s3, unsigned short* __restrict__ d3,
                            const float* __restrict__ s4, unsigned short* __restrict__ d4,
                            const float* __restrict__ s5, unsigned short* __restrict__ d5)
{
  int i = blockIdx.x * 256 + threadIdx.x;
  const float* src; unsigned short* dst; int k;
  if      (i < 19200)  { src = s0; dst = d0; k = i; }
  else if (i < 41700)  { src = s1; dst = d1; k = i - 19200; }
  else if (i < 64200)  { src = s2; dst = d2; k = i - 41700; }
  else if (i < 86700)  { src = s3; dst = d3; k = i - 64200; }
  else if (i < 240300) { src = s4; dst = d4; k = i - 86700; }
  else if (i < 393900) { src = s5; dst = d5; k = i - 240300; }
  else return;
  f32x4 v = *(const f32x4*)&src[k * 4];
  u16x4 o;
  #pragma unroll
  for (int j = 0; j < 4; j++) o[j] = f2bf(v[j]);
  *(u16x4*)&dst[k * 4] = o;
}

// ---------------------------------------------------------------- char CNN (per-word, bf16 out)
__global__ __launch_bounds__(256) void conv_kernel(
    const int* __restrict__ char_ids, const float* __restrict__ char_embed,
    const float* __restrict__ w2, const float* __restrict__ b2,
    const float* __restrict__ w3, const float* __restrict__ b3,
    const float* __restrict__ w4, const float* __restrict__ b4,
    const float* __restrict__ w5, const float* __restrict__ b5,
    unsigned short* __restrict__ ch)
{
  __shared__ __align__(16) float xT[CED][WCH];
  int wi = blockIdx.x;
  int tid = threadIdx.x;
  for (int e = tid; e < WCH * CED; e += 256) {
    int p = e / CED, c = e - p * CED;
    int cid = char_ids[wi * WCH + p];
    xT[c][p] = char_embed[cid * CED + c];
  }
  __syncthreads();
  int w = tid >> 6, f = tid & 63;
  int k = w + 2;
  int P = WCH - k + 1;
  const float* cw = (w == 0) ? w2 : (w == 1) ? w3 : (w == 2) ? w4 : w5;
  const float* cb = (w == 0) ? b2 : (w == 1) ? b3 : (w == 2) ? b4 : b5;
  float acc[19];
  #pragma unroll
  for (int p = 0; p < 19; p++) acc[p] = 0.f;
  for (int c = 0; c < CED; c++) {
    float xr[20];
    const float4* rowp = (const float4*)&xT[c][0];
    #pragma unroll
    for (int q = 0; q < 5; q++) {
      float4 v = rowp[q];
      xr[4*q+0] = v.x; xr[4*q+1] = v.y; xr[4*q+2] = v.z; xr[4*q+3] = v.w;
    }
    #pragma unroll
    for (int dw = 0; dw < 5; dw++) {
      if (dw < k) {
        float wv = cw[(dw * CED + c) * NFLT + f];
        #pragma unroll
        for (int p = 0; p < 19; p++) {
          if (p < P) acc[p] += xr[p + dw] * wv;
        }
      }
    }
  }
  float m = acc[0];
  #pragma unroll
  for (int p = 1; p < 19; p++) if (p < P) m = fmaxf(m, acc[p]);
  ch[wi * 256 + w * 64 + f] = f2bf(fmaxf(0.f, m + cb[f]));
}

// ---------------------------------------------------------------- word gather (bf16 out)
__global__ void gather_word_kernel(const int* __restrict__ token_ids,
                                   const float* __restrict__ word_embed,
                                   unsigned short* __restrict__ word_in)
{
  int idx = blockIdx.x * 256 + threadIdx.x;
  if (idx < NWORD * WDIM) {
    int i = idx / WDIM, c = idx - i * WDIM;
    word_in[idx] = f2bf(word_embed[token_ids[i] * WDIM + c]);
  }
}

// ---------------------------------------------------------------- bf16 GEMM, 256x128 tile, dual-A/B concat-K, split bias
__global__ __launch_bounds__(512) void gemm2_kernel(
    const unsigned short* __restrict__ A1, const unsigned short* __restrict__ A2,
    const unsigned short* __restrict__ B1, const unsigned short* __restrict__ B2,
    const float* __restrict__ bias, const float* __restrict__ bias2, int nsplit,
    unsigned short* __restrict__ Cbf,
    int M, int N, int K1, int K2, int act, int gridN)
{
  const int Kt = K1 + K2;
  __shared__ __align__(16) unsigned short As[256 * 40];
  __shared__ __align__(16) unsigned short Bs[128 * 40];
  int bid = blockIdx.x;
  int tm = bid / gridN, tn = bid - tm * gridN;
  int m0 = tm * 256, n0 = tn * 128;
  int tid = threadIdx.x;
  int lane = tid & 63, w = tid >> 6;
  int wr = (w >> 1) * 64, wc = (w & 1) * 64;
  f32x4 acc[4][4] = {};
  int fr = lane & 15, fk = (lane >> 4) * 8;

  for (int k0 = 0; k0 < Kt; k0 += 32) {
    __syncthreads();
    #pragma unroll
    for (int i = 0; i < 4; i++) {
      int q = tid + i * 512;
      int r = q >> 3, c4 = q & 7;
      int kx = k0 + c4 * 4;
      int ra = m0 + r;
      u16x4 v = {0, 0, 0, 0};
      if (kx < Kt && ra < M) {
        v = (kx < K1) ? *(const u16x4*)&A1[(size_t)ra * K1 + kx]
                      : *(const u16x4*)&A2[(size_t)ra * K2 + (kx - K1)];
      }
      *(u16x4*)&As[r * 40 + c4 * 4] = v;
    }
    #pragma unroll
    for (int i = 0; i < 2; i++) {
      int q = tid + i * 512;
      int r = q >> 3, c4 = q & 7;
      int kx = k0 + c4 * 4;
      int rb = n0 + r;
      u16x4 v = {0, 0, 0, 0};
      if (kx < Kt && rb < N) {
        v = (kx < K1) ? *(const u16x4*)&B1[(size_t)rb * K1 + kx]
                      : *(const u16x4*)&B2[(size_t)rb * K2 + (kx - K1)];
      }
      *(u16x4*)&Bs[r * 40 + c4 * 4] = v;
    }
    __syncthreads();
    bf16x8 a[4], b[4];
    #pragma unroll
    for (int mt = 0; mt < 4; mt++)
      a[mt] = *(const bf16x8*)&As[(wr + mt * 16 + fr) * 40 + fk];
    #pragma unroll
    for (int nt = 0; nt < 4; nt++)
      b[nt] = *(const bf16x8*)&Bs[(wc + nt * 16 + fr) * 40 + fk];
    #pragma unroll
    for (int mt = 0; mt < 4; mt++)
      #pragma unroll
      for (int nt = 0; nt < 4; nt++)
        acc[mt][nt] = __builtin_amdgcn_mfma_f32_16x16x32_bf16(a[mt], b[nt], acc[mt][nt], 0, 0, 0);
  }

  #pragma unroll
  for (int mt = 0; mt < 4; mt++) {
    #pragma unroll
    for (int nt = 0; nt < 4; nt++) {
      #pragma unroll
      for (int j = 0; j < 4; j++) {
        int row = m0 + wr + mt * 16 + (lane >> 4) * 4 + j;
        int col = n0 + wc + nt * 16 + (lane & 15);
        if (row < M && col < N) {
          float v = acc[mt][nt][j];
          if (bias) v += (col < nsplit) ? bias[col] : bias2[col - nsplit];
          if (act == 1)      v = tanhf(v);
          else if (act == 2) v = sigf(v);
          Cbf[(size_t)row * N + col] = f2bf(v);
        }
      }
    }
  }
}

// ---------------------------------------------------------------- gate combine (bf16) + flag reset
__global__ void feats_kernel(const unsigned short* __restrict__ g,
                             const unsigned short* __restrict__ word_in,
                             const unsigned short* __restrict__ char_in,
                             unsigned short* __restrict__ feats,
                             unsigned* __restrict__ flags)
{
  if (blockIdx.x == 0 && threadIdx.x < 32)
    __hip_atomic_store(&flags[threadIdx.x], 0u, __ATOMIC_RELAXED, __HIP_MEMORY_SCOPE_AGENT);
  int idx = blockIdx.x * 256 + threadIdx.x;
  if (idx < NWORD * WDIM) {
    float gg = bf2f(g[idx]);
    feats[idx] = f2bf(gg * bf2f(word_in[idx]) + (1.f - gg) * bf2f(char_in[idx]));
  }
}

// ---------------------------------------------------------------- bidirectional LSTM (r8 fabric; xg stride 4096)
__global__ __launch_bounds__(512, 2) void lstm_kernel(
    const unsigned short* __restrict__ xg_all,
    const float* __restrict__ whh_f, const float* __restrict__ whh_b,
    const int* __restrict__ lens,
    unsigned short* __restrict__ lstm_out, unsigned short* __restrict__ h_glob,
    unsigned* __restrict__ flags)
{
  int bid = blockIdx.x;
  int dir = bid >> 3, sl = bid & 7;
  int hs0 = sl << 6;
  int tid = threadIdx.x, lane = tid & 63, w = tid >> 6;
  int g = w & 3, hc = w >> 2;
  int l31 = lane & 31, le = lane >> 5;
  const unsigned short* xg = xg_all + dir * 2048;   // cols [dir*2048, +2048) of [NWORD][4096]
  const float* whh = dir ? whh_b : whh_f;
  unsigned short* hg = h_glob + dir * (2 * NB * HD);
  unsigned* myflags = flags + dir * 16;

  bf16x8 wf[32];
  {
    const float* src = whh + (size_t)(g * HD + hs0 + hc * 32 + l31) * HD + le * 8;
    #pragma unroll
    for (int kk = 0; kk < 32; kk++) {
      u16x8 tv;
      #pragma unroll
      for (int j = 0; j < 8; j++) tv[j] = f2bf(src[kk * 16 + j]);
      wf[kk] = __builtin_bit_cast(bf16x8, tv);
    }
  }

  __shared__ __align__(16) unsigned short hS[16384];
  __shared__ float Gs[NB][260];

  int b = tid >> 4;
  int u = (tid & 15) << 2;
  int srow = tid >> 4, sq = tid & 15;
  int mylen = lens[b];
  float c4[4] = {0.f,0.f,0.f,0.f}, hp4[4] = {0.f,0.f,0.f,0.f};

  ull xq0, xq1, xq2, xq3;
  {
    int t0 = dir ? (SEQ - 1) : 0;
    const ull* xp = (const ull*)&xg[((size_t)(b * SEQ + t0)) * 4096 + hs0 + u];
    xq0 = xp[0]; xq1 = xp[128]; xq2 = xp[256]; xq3 = xp[384];
  }

  for (int s = 0; s < SEQ; s++) {
    int t = dir ? (SEQ - 1 - s) : s;
    f32x16 acc0 = {}, acc1 = {};

    if (s > 0) {
      if (w == 0) {
        unsigned tgt = (unsigned)s;
        for (;;) {
          unsigned v = (lane < 8)
            ? __hip_atomic_load(&myflags[lane], __ATOMIC_RELAXED, __HIP_MEMORY_SCOPE_AGENT)
            : tgt;
          if (__all(v >= tgt)) break;
          __builtin_amdgcn_s_sleep(1);
        }
      }
      __syncthreads();                       // B1
      {
        const ull* hq = (const ull*)(hg + (s & 1) * (NB * HD));
        ull v[8];
        #pragma unroll
        for (int i = 0; i < 8; i++)
          v[i] = __hip_atomic_load(hq + srow * 128 + sq * 8 + i, __ATOMIC_RELAXED, __HIP_MEMORY_SCOPE_AGENT);
        int rs = ((srow ^ (sq & 7)) & 31) << 4;
        #pragma unroll
        for (int e2 = 0; e2 < 4; e2++) {
          int kk = 2 * sq + (e2 >> 1), e = e2 & 1;
          uint4 qv;
          qv.x = (unsigned)v[2*e2];     qv.y = (unsigned)(v[2*e2] >> 32);
          qv.z = (unsigned)v[2*e2+1];   qv.w = (unsigned)(v[2*e2+1] >> 32);
          *(uint4*)((char*)hS + (((kk * 2 + e) << 9) + rs)) = qv;
        }
      }
      __syncthreads();                       // B2
      #pragma unroll
      for (int kk = 0; kk < 32; kk += 2) {
        int rs = ((l31 ^ ((kk >> 1) & 7)) & 31) << 4;
        int a0off = ((kk * 2 + le) << 9) + rs;
        int a1off = ((kk * 2 + 2 + le) << 9) + rs;
        bf16x8 a0 = *(const bf16x8*)((const char*)hS + a0off);
        bf16x8 a1 = *(const bf16x8*)((const char*)hS + a1off);
        acc0 = __builtin_amdgcn_mfma_f32_32x32x16_bf16(a0, wf[kk], acc0, 0, 0, 0);
        acc1 = __builtin_amdgcn_mfma_f32_32x32x16_bf16(a1, wf[kk+1], acc1, 0, 0, 0);
      }
    }

    #pragma unroll
    for (int r = 0; r < 16; r++) {
      int bb = (r & 3) + 8 * (r >> 2) + 4 * le;
      Gs[bb][g * 64 + hc * 32 + l31] = acc0[r] + acc1[r];
    }
    __syncthreads();                         // B3

    f32x4 gi  = *(const f32x4*)&Gs[b][u];
    f32x4 gfv = *(const f32x4*)&Gs[b][64 + u];
    f32x4 ggv = *(const f32x4*)&Gs[b][128 + u];
    f32x4 gov = *(const f32x4*)&Gs[b][192 + u];
    bool mk = (t < mylen);
    ull hpk = 0, opk = 0;
    #pragma unroll
    for (int j = 0; j < 4; j++) {
      float xi = bf2f((unsigned short)(xq0 >> (16*j)));
      float xf = bf2f((unsigned short)(xq1 >> (16*j)));
      float xG = bf2f((unsigned short)(xq2 >> (16*j)));
      float xo = bf2f((unsigned short)(xq3 >> (16*j)));
      float iv = sigf(xi + gi[j]);
      float fv = sigf(xf + gfv[j]);
      float Gv = tanhf(xG + ggv[j]);
      float ov = sigf(xo + gov[j]);
      float cn = fv * c4[j] + iv * Gv;
      float hn = ov * tanhf(cn);
      if (mk) c4[j] = cn;
      float hk = mk ? hn : hp4[j];
      hp4[j] = hk;
      opk |= ((ull)f2bf(mk ? hn : 0.f)) << (16*j);
      hpk |= ((ull)f2bf(hk)) << (16*j);
    }
    {
      ull* hd = (ull*)(hg + ((s & 1) ^ 1) * (NB * HD));
      __hip_atomic_store(&hd[(b * HD + hs0 + u) >> 2], hpk, __ATOMIC_RELAXED, __HIP_MEMORY_SCOPE_AGENT);
    }

    __syncthreads();                         // B4: drains all waves' h stores to L3
    if (tid == 0)
      __hip_atomic_store(&myflags[sl], (unsigned)(s + 1), __ATOMIC_RELAXED, __HIP_MEMORY_SCOPE_AGENT);

    // off-critical-path: bf16 lstm_out store + next-step xg prefetch
    size_t obase = ((size_t)(b * SEQ + t)) * 1024 + dir * HD + hs0 + u;
    *(ull*)&lstm_out[obase] = opk;
    if (s + 1 < SEQ) {
      int tn = dir ? (SEQ - 2 - s) : (s + 1);
      const ull* xp = (const ull*)&xg[((size_t)(b * SEQ + tn)) * 4096 + hs0 + u];
      xq0 = xp[0]; xq1 = xp[128]; xq2 = xp[256]; xq3 = xp[384];
    }
  }
}

// ---------------------------------------------------------------- output projection + NEG pads (bf16 in)
__global__ __launch_bounds__(64) void logits_kernel(
    const unsigned short* __restrict__ lstm_out, const float* __restrict__ out_w,
    const float* __restrict__ out_b, float* __restrict__ lg)
{
  int rw = blockIdx.x, j = threadIdx.x;
  const unsigned short* row = lstm_out + (size_t)rw * 1024;
  u16x8 v0 = *(const u16x8*)&row[j * 16];
  u16x8 v1 = *(const u16x8*)&row[j * 16 + 8];
  float s[9];
  #pragma unroll
  for (int l = 0; l < 9; l++) s[l] = 0.f;
  #pragma unroll
  for (int k = 0; k < 8; k++) {
    float x = bf2f(v0[k]);
    int e = j * 16 + k;
    #pragma unroll
    for (int l = 0; l < 9; l++) s[l] += x * out_w[l * 1024 + e];
  }
  #pragma unroll
  for (int k = 0; k < 8; k++) {
    float x = bf2f(v1[k]);
    int e = j * 16 + 8 + k;
    #pragma unroll
    for (int l = 0; l < 9; l++) s[l] += x * out_w[l * 1024 + e];
  }
  #pragma unroll
  for (int l = 0; l < 9; l++) {
    #pragma unroll
    for (int off = 32; off > 0; off >>= 1) s[l] += __shfl_xor(s[l], off);
  }
  float v = NEGV;
  if (j < 9) {
    float r = (j==0)?s[0]:(j==1)?s[1]:(j==2)?s[2]:(j==3)?s[3]:(j==4)?s[4]:
              (j==5)?s[5]:(j==6)?s[6]:(j==7)?s[7]:s[8];
    v = r + out_b[j];
  }
  if (j < LPAD) lg[(size_t)rw * LPAD + j] = v;
}

// ---------------------------------------------------------------- CRF: gold + norm + loglik (merged)
__global__ __launch_bounds__(64) void crf_kernel(
    const float* __restrict__ lg, const int* __restrict__ labels,
    const int* __restrict__ lens, const float* __restrict__ trn, float* __restrict__ out_ll)
{
  int b = blockIdx.x, i = threadIdx.x;
  int len = lens[b];
  const int* lab = labels + b * SEQ;
  const float* l0 = lg + (size_t)b * SEQ * LPAD;

  float gs = 0.f;
  for (int t = i; t < SEQ; t += 64) {
    if (t < len) {
      gs += l0[t * LPAD + lab[t]];
      if (t >= 1) gs += trn[lab[t] * LPAD + lab[t - 1]];
    }
  }
  #pragma unroll
  for (int off = 32; off > 0; off >>= 1) gs += __shfl_xor(gs, off);
  gs += trn[lab[0] * LPAD + 9];
  gs += trn[10 * LPAD + lab[len - 1]];

  bool act = (i < LPAD);
  float trow[LPAD];
  #pragma unroll
  for (int jj = 0; jj < LPAD; jj++) trow[jj] = act ? trn[i * LPAD + jj] : 0.f;
  float alpha = act ? (l0[i] + trow[9]) : -1e30f;

  for (int t = 1; t < SEQ; t++) {
    float vj[LPAD];
    #pragma unroll
    for (int jj = 0; jj < LPAD; jj++) vj[jj] = __shfl(alpha, jj) + trow[jj];
    float mx = vj[0];
    #pragma unroll
    for (int jj = 1; jj < LPAD; jj++) mx = fmaxf(mx, vj[jj]);
    float sum = 0.f;
    #pragma unroll
    for (int jj = 0; jj < LPAD; jj++) sum += expf(vj[jj] - mx);
    float lgv = act ? l0[t * LPAD + i] : 0.f;
    float nw = mx + logf(sum) + lgv;
    if (act && t < len) alpha = nw;
  }
  float vj[LPAD];
  #pragma unroll
  for (int jj = 0; jj < LPAD; jj++) vj[jj] = __shfl(alpha, jj) + trn[10 * LPAD + jj];
  float mx = vj[0];
  #pragma unroll
  for (int jj = 1; jj < LPAD; jj++) mx = fmaxf(mx, vj[jj]);
  float sum = 0.f;
  #pragma unroll
  for (int jj = 0; jj < LPAD; jj++) sum += expf(vj[jj] - mx);
  if (i == 0) out_ll[b] = gs - (mx + logf(sum));
}

// ================================================================ launch
extern "C" void kernel_launch(void* const* d_in, const int* in_sizes, int n_in,
                              void* d_out, int out_size, void* d_ws, size_t ws_size,
                              hipStream_t stream)
{
  (void)in_sizes; (void)n_in; (void)out_size; (void)ws_size;
  const int*   token_ids = (const int*)d_in[0];
  const int*   char_ids  = (const int*)d_in[1];
  const int*   lens      = (const int*)d_in[2];
  const int*   labels    = (const int*)d_in[3];
  const float* word_embed= (const float*)d_in[4];
  const float* char_embed= (const float*)d_in[5];
  const float* w2 = (const float*)d_in[6];  const float* cb2 = (const float*)d_in[7];
  const float* w3 = (const float*)d_in[8];  const float* cb3 = (const float*)d_in[9];
  const float* w4 = (const float*)d_in[10]; const float* cb4 = (const float*)d_in[11];
  const float* w5 = (const float*)d_in[12]; const float* cb5 = (const float*)d_in[13];
  const float* ff_w = (const float*)d_in[14]; const float* ff_b = (const float*)d_in[15];
  const float* wgate_w = (const float*)d_in[16];
  const float* cgate_w = (const float*)d_in[17];
  const float* gate_w  = (const float*)d_in[18];
  const float* wih_f = (const float*)d_in[19]; const float* whh_f = (const float*)d_in[20];
  const float* b_f   = (const float*)d_in[21];
  const float* wih_b = (const float*)d_in[22]; const float* whh_b = (const float*)d_in[23];
  const float* b_b   = (const float*)d_in[24];
  const float* out_w = (const float*)d_in[25]; const float* out_b = (const float*)d_in[26];
  const float* trn   = (const float*)d_in[27];

  char* ws = (char*)d_ws;
  size_t off = 0;
  auto alloc = [&](size_t bytes) { void* p = ws + off; off += (bytes + 255) & ~(size_t)255; return p; };
  unsigned short* ch_bf    = (unsigned short*)alloc((size_t)NWORD * 256 * 2);
  unsigned short* word_bf  = (unsigned short*)alloc((size_t)NWORD * WDIM * 2);
  unsigned short* char_bf  = (unsigned short*)alloc((size_t)NWORD * WDIM * 2);
  unsigned short* t1_bf    = (unsigned short*)alloc((size_t)NWORD * WDIM * 2);
  unsigned short* g_bf     = (unsigned short*)alloc((size_t)NWORD * WDIM * 2);
  unsigned short* feats_bf = (unsigned short*)alloc((size_t)NWORD * WDIM * 2);
  unsigned short* ffw_bf   = (unsigned short*)alloc((size_t)300 * 256 * 2);
  unsigned short* wgw_bf   = (unsigned short*)alloc((size_t)300 * 300 * 2);
  unsigned short* cgw_bf   = (unsigned short*)alloc((size_t)300 * 300 * 2);
  unsigned short* gw_bf    = (unsigned short*)alloc((size_t)300 * 300 * 2);
  // wih_all: [4096][300] bf16 — wihf rows 0..2047, wihb rows 2048..4095 (contiguous:
  // 2048*300*2 = 1,228,800 B = 4800*256, so the 256B-align adds no padding).
  unsigned short* wihf_bf  = (unsigned short*)alloc((size_t)2048 * 300 * 2);
  unsigned short* wihb_bf  = (unsigned short*)alloc((size_t)2048 * 300 * 2);
  unsigned short* xg_all   = (unsigned short*)alloc((size_t)NWORD * 4096 * 2);
  unsigned short* lstm_o   = (unsigned short*)alloc((size_t)NWORD * 1024 * 2);
  unsigned short* hglob    = (unsigned short*)alloc((size_t)2 * 2 * NB * HD * 2);
  unsigned* flags = (unsigned*)alloc(256);

  float* outp   = (float*)d_out;
  float* loglik = outp;
  float* logits = outp + NB;

  conv_kernel<<<NWORD, 256, 0, stream>>>(char_ids, char_embed, w2, cb2, w3, cb3, w4, cb4, w5, cb5, ch_bf);
  gather_word_kernel<<<(NWORD * WDIM + 255) / 256, 256, 0, stream>>>(token_ids, word_embed, word_bf);
  cvt6_kernel<<<(393900 + 255) / 256, 256, 0, stream>>>(ff_w, ffw_bf, wgate_w, wgw_bf, cgate_w, cgw_bf,
                                                        gate_w, gw_bf, wih_f, wihf_bf, wih_b, wihb_bf);
  // char_in = ch @ ff_w^T + ff_b
  gemm2_kernel<<<16 * 3, 512, 0, stream>>>(ch_bf, ch_bf, ffw_bf, ffw_bf, ff_b, ff_b, 300, char_bf,
                                           NWORD, 300, 256, 0, 0, 3);
  // t1 = tanh(word @ wgate^T + char @ cgate^T)
  gemm2_kernel<<<16 * 3, 512, 0, stream>>>(word_bf, char_bf, wgw_bf, cgw_bf, nullptr, nullptr, 300, t1_bf,
                                           NWORD, 300, 300, 300, 1, 3);
  // g = sigmoid(t1 @ gate_w^T)
  gemm2_kernel<<<16 * 3, 512, 0, stream>>>(t1_bf, t1_bf, gw_bf, gw_bf, nullptr, nullptr, 300, g_bf,
                                           NWORD, 300, 300, 0, 2, 3);
  feats_kernel<<<(NWORD * WDIM + 255) / 256, 256, 0, stream>>>(g_bf, word_bf, char_bf, feats_bf, flags);
  // xg_all = feats @ [wih_f; wih_b]^T + [b_f; b_b]   (single merged GEMM, N=4096)
  gemm2_kernel<<<16 * 32, 512, 0, stream>>>(feats_bf, feats_bf, wihf_bf, wihf_bf, b_f, b_b, 2048, xg_all,
                                            NWORD, 4096, 300, 0, 0, 32);
  {
    void* args[] = { (void*)&xg_all, (void*)&whh_f, (void*)&whh_b,
                     (void*)&lens, (void*)&lstm_o, (void*)&hglob, (void*)&flags };
    hipLaunchCooperativeKernel((void*)lstm_kernel, dim3(LSTM_BLOCKS), dim3(512), args, 0, stream);
  }
  logits_kernel<<<NWORD, 64, 0, stream>>>(lstm_o, out_w, out_b, logits);
  crf_kernel<<<NB, 64, 0, stream>>>(logits, labels, lens, trn, loglik);
}